// Round 2
// baseline (444.507 us; speedup 1.0000x reference)
//
#include <hip/hip_runtime.h>
#include <stdint.h>

#define S_LEN 4096
#define DM 1024
#define NH 16
#define DKH 64

typedef __attribute__((ext_vector_type(8))) __bf16 bf16x8;
typedef __attribute__((ext_vector_type(8))) short s16x8;
typedef __attribute__((ext_vector_type(4))) float f32x4;

__device__ inline unsigned short f2bf(float f) {
  unsigned int u = __builtin_bit_cast(unsigned int, f);
  u += 0x7fff + ((u >> 16) & 1);   // RNE
  return (unsigned short)(u >> 16);
}

__device__ inline f32x4 mfma16(s16x8 a, s16x8 b, f32x4 c) {
  return __builtin_amdgcn_mfma_f32_16x16x32_bf16(
      __builtin_bit_cast(bf16x8, a), __builtin_bit_cast(bf16x8, b), c, 0, 0, 0);
}

__device__ inline void gld_lds16(const unsigned short* g, unsigned short* l) {
  __builtin_amdgcn_global_load_lds(
      (const __attribute__((address_space(1))) unsigned int*)g,
      (__attribute__((address_space(3))) unsigned int*)l, 16, 0, 0);
}

__global__ void convert_f32_bf16(const float* __restrict__ in,
                                 unsigned short* __restrict__ out, int n4) {
  int i = blockIdx.x * blockDim.x + threadIdx.x;
  if (i >= n4) return;
  float4 v = reinterpret_cast<const float4*>(in)[i];
  ushort4 o;
  o.x = f2bf(v.x); o.y = f2bf(v.y); o.z = f2bf(v.z); o.w = f2bf(v.w);
  reinterpret_cast<ushort4*>(out)[i] = o;
}

__device__ inline void storeC(unsigned short* C, size_t i, float v) { C[i] = f2bf(v); }
__device__ inline void storeC(float* C, size_t i, float v) { C[i] = v; }

// C[m][n] = sum_k A[m][k] * B[n][k]   (torch Linear: y = x @ W^T)
// 128x128 tile, BK=64, 4 waves (2x2), each wave 64x64 = 4x4 frags of 16x16.
template <typename OutT>
__global__ __launch_bounds__(256) void gemm_bt(const unsigned short* __restrict__ A,
                                               const unsigned short* __restrict__ B,
                                               OutT* __restrict__ C, int M, int N, int K) {
  __shared__ __align__(16) unsigned short lds_a[128 * 64];
  __shared__ __align__(16) unsigned short lds_b[128 * 64];
  const int tid = threadIdx.x;
  const int lane = tid & 63;
  const int w = tid >> 6;
  const int wr = w >> 1, wc = w & 1;
  const int l15 = lane & 15, lhi = lane >> 4;
  const int bm0 = blockIdx.x * 128, bn0 = blockIdx.y * 128;
  const int srow = lane >> 3;       // 0..7: row within the wave's 8-row stripe
  const int scol = (lane & 7) * 8;  // element col within BK=64

  f32x4 acc[4][4] = {};

  for (int k0 = 0; k0 < K; k0 += 64) {
    __syncthreads();
#pragma unroll
    for (int i = 0; i < 4; ++i) {
      const int base = i * 2048 + w * 512;       // element offset of wave-uniform LDS base
      const int row = i * 32 + w * 8 + srow;     // tile row this lane fetches
      gld_lds16(A + (size_t)(bm0 + row) * K + k0 + scol, lds_a + base);
      gld_lds16(B + (size_t)(bn0 + row) * K + k0 + scol, lds_b + base);
    }
    __syncthreads();   // compiler drains vmcnt before s_barrier
#pragma unroll
    for (int kk = 0; kk < 2; ++kk) {
      s16x8 af[4], bfr[4];
#pragma unroll
      for (int mi = 0; mi < 4; ++mi)
        af[mi] = *(const s16x8*)&lds_a[(wr * 64 + mi * 16 + l15) * 64 + kk * 32 + lhi * 8];
#pragma unroll
      for (int ni = 0; ni < 4; ++ni)
        bfr[ni] = *(const s16x8*)&lds_b[(wc * 64 + ni * 16 + l15) * 64 + kk * 32 + lhi * 8];
#pragma unroll
      for (int mi = 0; mi < 4; ++mi)
#pragma unroll
        for (int ni = 0; ni < 4; ++ni)
          acc[mi][ni] = mfma16(af[mi], bfr[ni], acc[mi][ni]);
    }
  }
#pragma unroll
  for (int mi = 0; mi < 4; ++mi)
#pragma unroll
    for (int ni = 0; ni < 4; ++ni)
#pragma unroll
      for (int r = 0; r < 4; ++r) {
        int row = bm0 + wr * 64 + mi * 16 + lhi * 4 + r;
        int col = bn0 + wc * 64 + ni * 16 + l15;
        storeC(C, (size_t)row * N + col, acc[mi][ni][r]);
      }
}

// Flash-style causal attention over the fused QKV buffer [S][3*DM].
// Grid: (S/64, NH). 4 waves; wave w owns q-rows [qb + 16w, +16).
__global__ __launch_bounds__(256) void attn_causal(const unsigned short* __restrict__ QKV,
                                                   unsigned short* __restrict__ CTX) {
  const int qt = blockIdx.x;
  const int h = blockIdx.y;
  const int tid = threadIdx.x;
  const int lane = tid & 63, w = tid >> 6;
  const int l15 = lane & 15, lhi = lane >> 4;
  const int qb = qt * 64;
  const int qrow0 = qb + w * 16;
  const int LDQ = 3 * DM;

  __shared__ __align__(16) unsigned short vt[64][72];        // V^T: [dk][key], +8 pad
  __shared__ __align__(16) unsigned short pbuf[4][16][72];   // per-wave P tile

  const unsigned short* Qp = QKV;
  const unsigned short* Kp = QKV + DM;
  const unsigned short* Vp = QKV + 2 * DM;

  // Q fragments (A-operand), loaded once
  s16x8 qf[2];
#pragma unroll
  for (int kk = 0; kk < 2; ++kk)
    qf[kk] = *(const s16x8*)&Qp[(size_t)(qrow0 + l15) * LDQ + h * DKH + kk * 32 + lhi * 8];

  f32x4 o[4] = {};
  float m_r[4], l_r[4];
#pragma unroll
  for (int r = 0; r < 4; ++r) { m_r[r] = -1e30f; l_r[r] = 0.f; }

  const int nkb = qt + 1;
  for (int kbi = 0; kbi < nkb; ++kbi) {
    const int kb = kbi * 64;
    __syncthreads();   // prev iteration's LDS reads done
    // stage V^T: thread t handles key=t>>2, dk0=(t&3)*16
    {
      const int key = tid >> 2, dk0 = (tid & 3) * 16;
      const unsigned short* src = &Vp[(size_t)(kb + key) * LDQ + h * DKH + dk0];
#pragma unroll
      for (int j = 0; j < 16; ++j) vt[dk0 + j][key] = src[j];
    }
    // S = Q K^T (B-operand read straight from global; K rows are K-contiguous)
    f32x4 sf[4];
#pragma unroll
    for (int st = 0; st < 4; ++st) {
      f32x4 accs = {};
#pragma unroll
      for (int kk = 0; kk < 2; ++kk) {
        s16x8 kf = *(const s16x8*)&Kp[(size_t)(kb + st * 16 + l15) * LDQ + h * DKH + kk * 32 + lhi * 8];
        accs = mfma16(qf[kk], kf, accs);
      }
      sf[st] = accs;
    }
    // scale + causal mask + online softmax
    float mt[4];
#pragma unroll
    for (int r = 0; r < 4; ++r) {
      const int qrow = qrow0 + lhi * 4 + r;
      float mx = -1e30f;
#pragma unroll
      for (int st = 0; st < 4; ++st) {
        const int key = kb + st * 16 + l15;
        float s = (key <= qrow) ? sf[st][r] * 0.125f : -1e30f;
        sf[st][r] = s;
        mx = fmaxf(mx, s);
      }
#pragma unroll
      for (int d = 1; d < 16; d <<= 1) mx = fmaxf(mx, __shfl_xor(mx, d));
      mt[r] = mx;
    }
    float alpha[4];
#pragma unroll
    for (int r = 0; r < 4; ++r) {
      const float mn = fmaxf(m_r[r], mt[r]);
      alpha[r] = __expf(m_r[r] - mn);
      m_r[r] = mn;
      float rs = 0.f;
#pragma unroll
      for (int st = 0; st < 4; ++st) {
        const float p = __expf(sf[st][r] - mn);
        sf[st][r] = p;
        rs += p;
      }
#pragma unroll
      for (int d = 1; d < 16; d <<= 1) rs += __shfl_xor(rs, d);
      l_r[r] = l_r[r] * alpha[r] + rs;
    }
#pragma unroll
    for (int n = 0; n < 4; ++n) {
      f32x4 t = o[n];
#pragma unroll
      for (int r = 0; r < 4; ++r) t[r] *= alpha[r];
      o[n] = t;
    }
    // P -> LDS (bf16), per-wave region
#pragma unroll
    for (int st = 0; st < 4; ++st)
#pragma unroll
      for (int r = 0; r < 4; ++r)
        pbuf[w][lhi * 4 + r][st * 16 + l15] = f2bf(sf[st][r]);
    __syncthreads();   // vt staged + pbuf visible
    // O += P V
#pragma unroll
    for (int kk = 0; kk < 2; ++kk) {
      s16x8 pa = *(const s16x8*)&pbuf[w][l15][kk * 32 + lhi * 8];
#pragma unroll
      for (int n = 0; n < 4; ++n) {
        s16x8 vb = *(const s16x8*)&vt[n * 16 + l15][kk * 32 + lhi * 8];
        o[n] = mfma16(pa, vb, o[n]);
      }
    }
  }
  // epilogue: O / l, store bf16 ctx in [S][DM] layout
#pragma unroll
  for (int n = 0; n < 4; ++n)
#pragma unroll
    for (int r = 0; r < 4; ++r) {
      const int qrow = qrow0 + lhi * 4 + r;
      CTX[(size_t)qrow * DM + h * DKH + n * 16 + l15] = f2bf(o[n][r] / l_r[r]);
    }
}

extern "C" void kernel_launch(void* const* d_in, const int* in_sizes, int n_in,
                              void* d_out, int out_size, void* d_ws, size_t ws_size,
                              hipStream_t stream) {
  const float* x  = (const float*)d_in[0];
  const float* Wq = (const float*)d_in[1];
  const float* Wk = (const float*)d_in[2];
  const float* Wv = (const float*)d_in[3];
  const float* Wo = (const float*)d_in[4];
  float* out = (float*)d_out;
  char* ws = (char*)d_ws;

  unsigned short* x_bf  = (unsigned short*)(ws + 0);
  unsigned short* wqkv  = (unsigned short*)(ws + (size_t)8 * 1024 * 1024);   // [3*DM][DM]
  unsigned short* wo_bf = (unsigned short*)(ws + (size_t)14 * 1024 * 1024);  // [DM][DM]
  unsigned short* qkv   = (unsigned short*)(ws + (size_t)16 * 1024 * 1024);  // [S][3*DM]
  unsigned short* ctx   = (unsigned short*)(ws + (size_t)40 * 1024 * 1024);  // [S][DM]

  const int n4x = S_LEN * DM / 4;
  convert_f32_bf16<<<(n4x + 255) / 256, 256, 0, stream>>>(x, x_bf, n4x);
  const int w4 = DM * DM / 4;
  convert_f32_bf16<<<(w4 + 255) / 256, 256, 0, stream>>>(Wq, wqkv, w4);
  convert_f32_bf16<<<(w4 + 255) / 256, 256, 0, stream>>>(Wk, wqkv + DM * DM, w4);
  convert_f32_bf16<<<(w4 + 255) / 256, 256, 0, stream>>>(Wv, wqkv + 2 * DM * DM, w4);
  convert_f32_bf16<<<(w4 + 255) / 256, 256, 0, stream>>>(Wo, wo_bf, w4);

  dim3 g1(S_LEN / 128, (3 * DM) / 128);
  gemm_bt<unsigned short><<<g1, 256, 0, stream>>>(x_bf, wqkv, qkv, S_LEN, 3 * DM, DM);

  dim3 g2(S_LEN / 64, NH);
  attn_causal<<<g2, 256, 0, stream>>>(qkv, ctx);

  dim3 g3(S_LEN / 128, DM / 128);
  gemm_bt<float><<<g3, 256, 0, stream>>>(ctx, wo_bf, out, S_LEN, DM, DM);
}